// Round 1
// baseline (1159.278 us; speedup 1.0000x reference)
//
#include <hip/hip_runtime.h>
#include <hip/hip_bf16.h>
#include <stdint.h>

typedef unsigned short ushort_t;
typedef __attribute__((ext_vector_type(8))) short short8;
typedef __attribute__((ext_vector_type(4))) float float4v;
typedef __attribute__((ext_vector_type(8))) ushort_t ushort8;

#define BM 128
#define BN 128
#define BK 32

// ---------------------------------------------------------------------------
// async global->LDS 16B copy (wave-uniform LDS base + lane*16 semantics)
// ---------------------------------------------------------------------------
__device__ __forceinline__ void async_copy16(const void* g, void* l) {
  __builtin_amdgcn_global_load_lds(
      (__attribute__((address_space(1))) void*)g,
      (__attribute__((address_space(3))) void*)l,
      16, 0, 0);
}

// ---------------------------------------------------------------------------
// fp32 -> bf16 (RNE) conversion, 8 elements / thread, 16B stores
// ---------------------------------------------------------------------------
__device__ __forceinline__ ushort_t f32_to_bf16_rne(float f) {
  union { float f; uint32_t u; } v; v.f = f;
  uint32_t u = v.u;
  u += 0x7FFFu + ((u >> 16) & 1u);
  return (ushort_t)(u >> 16);
}

__global__ __launch_bounds__(256) void cvt_f32_bf16_kernel(
    const float* __restrict__ in, ushort_t* __restrict__ out, int n8) {
  int i = blockIdx.x * 256 + threadIdx.x;
  if (i >= n8) return;
  const float4v* in4 = (const float4v*)in;
  float4v a = in4[2 * i];
  float4v b = in4[2 * i + 1];
  ushort8 o;
  o[0] = f32_to_bf16_rne(a[0]); o[1] = f32_to_bf16_rne(a[1]);
  o[2] = f32_to_bf16_rne(a[2]); o[3] = f32_to_bf16_rne(a[3]);
  o[4] = f32_to_bf16_rne(b[0]); o[5] = f32_to_bf16_rne(b[1]);
  o[6] = f32_to_bf16_rne(b[2]); o[7] = f32_to_bf16_rne(b[3]);
  ((ushort8*)out)[i] = o;
}

// ---------------------------------------------------------------------------
// bf16 MFMA GEMM: C[M,N] = Xb[M,K] * Ab[N,K]^T + bias[N]   (m97 structure)
// 128x128 block tile, BK=32, 256 threads = 4 waves in 2x2, 64x64 per wave.
// ---------------------------------------------------------------------------
__global__ __launch_bounds__(256) void gemm_bf16_bt_kernel(
    const ushort_t* __restrict__ Xb,   // [M,K] bf16
    const ushort_t* __restrict__ Ab,   // [N,K] bf16
    const float* __restrict__ bias,    // [N]
    float* __restrict__ Y,             // [M,N] fp32
    int M, int N, int K) {
  __shared__ ushort_t As[BM * BK];   // 8 KiB
  __shared__ ushort_t Bs[BN * BK];   // 8 KiB

  const int tid  = threadIdx.x;
  const int lane = tid & 63;
  const int wave = tid >> 6;   // 0..3
  const int wrow = wave & 1;   // wave's 64-row slab
  const int wcol = wave >> 1;  // wave's 64-col slab

  const int m0 = blockIdx.y * BM;
  const int n0 = blockIdx.x * BN;

  // staging: each thread supplies one 16B chunk per half-tile (2 halves each)
  const int sr = tid >> 2;          // 0..63 (row within 64-row half)
  const int sc = (tid & 3) * 8;     // k-offset 0/8/16/24

  const ushort_t* gA0 = Xb + (size_t)(m0 + sr) * K + sc;
  const ushort_t* gA1 = Xb + (size_t)(m0 + 64 + sr) * K + sc;
  const ushort_t* gB0 = Ab + (size_t)(n0 + sr) * K + sc;
  const ushort_t* gB1 = Ab + (size_t)(n0 + 64 + sr) * K + sc;

  // wave-uniform LDS bases (hw scatters lane*16B)
  ushort_t* lA0 = As + wave * 512;
  ushort_t* lA1 = As + 2048 + wave * 512;
  ushort_t* lB0 = Bs + wave * 512;
  ushort_t* lB1 = Bs + 2048 + wave * 512;

  float4v acc[4][4];
#pragma unroll
  for (int i = 0; i < 4; ++i)
#pragma unroll
    for (int j = 0; j < 4; ++j) acc[i][j] = (float4v){0.f, 0.f, 0.f, 0.f};

  const int frow = lane & 15;          // fragment row/col within 16
  const int fq8  = (lane >> 4) * 8;    // k sub-offset per quad

  for (int k0 = 0; k0 < K; k0 += BK) {
    __syncthreads();  // previous iter's ds_reads done before overwrite
    async_copy16(gA0 + k0, lA0);
    async_copy16(gA1 + k0, lA1);
    async_copy16(gB0 + k0, lB0);
    async_copy16(gB1 + k0, lB1);
    __syncthreads();  // vmcnt drained by barrier -> LDS tile valid

    short8 af[4], bf[4];
#pragma unroll
    for (int mi = 0; mi < 4; ++mi)
      af[mi] = *(const short8*)&As[(wrow * 64 + mi * 16 + frow) * BK + fq8];
#pragma unroll
    for (int ni = 0; ni < 4; ++ni)
      bf[ni] = *(const short8*)&Bs[(wcol * 64 + ni * 16 + frow) * BK + fq8];

#pragma unroll
    for (int mi = 0; mi < 4; ++mi)
#pragma unroll
      for (int ni = 0; ni < 4; ++ni)
        acc[mi][ni] = __builtin_amdgcn_mfma_f32_16x16x32_bf16(
            af[mi], bf[ni], acc[mi][ni], 0, 0, 0);
  }

  // epilogue: C/D layout col=lane&15, row=(lane>>4)*4+reg  [m89-verified]
  const int cn = lane & 15;
  const int rq = (lane >> 4) * 4;
#pragma unroll
  for (int ni = 0; ni < 4; ++ni) {
    const int ncol = n0 + wcol * 64 + ni * 16 + cn;
    const float bv = bias[ncol];
#pragma unroll
    for (int mi = 0; mi < 4; ++mi) {
      const int mrow = m0 + wrow * 64 + mi * 16 + rq;
      float* yp = Y + (size_t)mrow * N + ncol;
#pragma unroll
      for (int r = 0; r < 4; ++r)
        yp[(size_t)r * N] = acc[mi][ni][r] + bv;
    }
  }
}

// ---------------------------------------------------------------------------
// fallback (only if ws_size is too small): naive fp32, correct but slow
// ---------------------------------------------------------------------------
__global__ __launch_bounds__(256) void naive_linear_kernel(
    const float* __restrict__ x, const float* __restrict__ A,
    const float* __restrict__ b, float* __restrict__ y,
    int M, int N, int K) {
  long long idx = (long long)blockIdx.x * 256 + threadIdx.x;
  if (idx >= (long long)M * N) return;
  int m = (int)(idx / N), n = (int)(idx % N);
  float s = b[n];
  const float* xp = x + (size_t)m * K;
  const float* ap = A + (size_t)n * K;
  for (int k = 0; k < K; ++k) s += xp[k] * ap[k];
  y[idx] = s;
}

// ---------------------------------------------------------------------------
extern "C" void kernel_launch(void* const* d_in, const int* in_sizes, int n_in,
                              void* d_out, int out_size, void* d_ws, size_t ws_size,
                              hipStream_t stream) {
  const float* x = (const float*)d_in[0];  // [8,2048,4096] -> [M,K]
  const float* A = (const float*)d_in[1];  // [N,K]
  const float* b = (const float*)d_in[2];  // [N]
  float* y = (float*)d_out;

  const int K = 4096;
  const int N = in_sizes[2];               // 4096
  const int M = in_sizes[0] / K;           // 16384

  const size_t x_elems = (size_t)M * K;
  const size_t a_elems = (size_t)N * K;
  const size_t needed = (x_elems + a_elems) * sizeof(ushort_t);

  if (ws_size >= needed) {
    ushort_t* xb = (ushort_t*)d_ws;
    ushort_t* ab = xb + x_elems;

    int nx8 = (int)(x_elems / 8);
    int na8 = (int)(a_elems / 8);
    cvt_f32_bf16_kernel<<<(nx8 + 255) / 256, 256, 0, stream>>>(x, xb, nx8);
    cvt_f32_bf16_kernel<<<(na8 + 255) / 256, 256, 0, stream>>>(A, ab, na8);

    dim3 grid(N / BN, M / BM);  // (32, 128)
    gemm_bf16_bt_kernel<<<grid, 256, 0, stream>>>(xb, ab, b, y, M, N, K);
  } else {
    long long total = (long long)M * N;
    naive_linear_kernel<<<(unsigned)((total + 255) / 256), 256, 0, stream>>>(
        x, A, b, y, M, N, K);
  }
}